// Round 5
// baseline (376.516 us; speedup 1.0000x reference)
//
#include <hip/hip_runtime.h>
#include <math.h>

#define RQ 6               // per-lane queue depth (fallback path only)
constexpr int WRANKS = 768; // phase-1 rank window (12 chunks of 64)
constexpr int WCH = 12;

typedef __attribute__((ext_vector_type(8))) short s8v;    // 8 bf16 (4 VGPRs)
typedef __attribute__((ext_vector_type(4))) float f32x4;  // MFMA acc

__device__ inline unsigned short f2bf(float x) {          // RNE f32->bf16
    const unsigned int u = __float_as_uint(x);
    return (unsigned short)((u + 0x7FFFu + ((u >> 16) & 1u)) >> 16);
}

// N(0,1) quantiles at i/64, i=1..63. PERF-ONLY hint; CSR uses exact counts.
__constant__ float ZB[63] = {
    -2.1539f, -1.8627f, -1.6759f, -1.5341f, -1.4178f, -1.3180f, -1.2299f, -1.1503f,
    -1.0775f, -1.0100f, -0.9468f, -0.8871f, -0.8305f, -0.7764f, -0.7245f, -0.6745f,
    -0.6261f, -0.5791f, -0.5334f, -0.4888f, -0.4451f, -0.4023f, -0.3601f, -0.3186f,
    -0.2776f, -0.2372f, -0.1971f, -0.1573f, -0.1178f, -0.0784f, -0.0392f,  0.0000f,
     0.0392f,  0.0784f,  0.1178f,  0.1573f,  0.1971f,  0.2372f,  0.2776f,  0.3186f,
     0.3601f,  0.4023f,  0.4451f,  0.4888f,  0.5334f,  0.5791f,  0.6261f,  0.6745f,
     0.7245f,  0.7764f,  0.8305f,  0.8871f,  0.9468f,  1.0100f,  1.0775f,  1.1503f,
     1.2299f,  1.3180f,  1.4178f,  1.5341f,  1.6759f,  1.8627f,  2.1539f };

// ---------------------------------------------------------------------------
// K0: z-bin CSR build. One block per (b,list): count -> prefix -> scatter.
// ---------------------------------------------------------------------------
__global__ __launch_bounds__(1024) void zbin_kernel(
    const float* __restrict__ p0, const float* __restrict__ p1,
    float4* __restrict__ sp, int* __restrict__ starts, int N)
{
    __shared__ int cnt[64], off[64], cur[64];
    const int t = threadIdx.x;
    const int bl = blockIdx.x;                    // b*2 + list
    const int b = bl >> 1, list = bl & 1;
    const float* rb = (list ? p1 : p0) + (size_t)(b * 3) * N;
    if (t < 64) { cnt[t] = 0; cur[t] = 0; }
    __syncthreads();
    int mybin[4]; float mx[4], my[4], mz[4];
    for (int i = 0; i < 4; ++i) {
        const int idx = i * 1024 + t;
        const float z = rb[2 * N + idx];
        mx[i] = rb[idx]; my[i] = rb[N + idx]; mz[i] = z;
        int bin = 0;
#pragma unroll
        for (int s = 32; s; s >>= 1)
            if (bin + s <= 63 && z >= ZB[bin + s - 1]) bin += s;
        mybin[i] = bin;
        atomicAdd(&cnt[bin], 1);
    }
    __syncthreads();
    if (t < 64) {                                 // wave 0: exclusive prefix
        const int v = cnt[t];
        int x = v;
#pragma unroll
        for (int o = 1; o < 64; o <<= 1) {
            const int y = __shfl_up(x, o);
            if (t >= o) x += y;
        }
        off[t] = x - v;
        starts[bl * 65 + t] = x - v;
        if (t == 63) starts[bl * 65 + 64] = x;
    }
    __syncthreads();
    for (int i = 0; i < 4; ++i) {
        const int bin = mybin[i];
        const int pos = off[bin] + atomicAdd(&cur[bin], 1);
        sp[(size_t)bl * 4096 + pos] =
            make_float4(mx[i], my[i], mz[i],
                        fmaf(mx[i], mx[i], fmaf(my[i], my[i], mz[i] * mz[i])));
    }
}

// ---------------------------------------------------------------------------
// K0b: query gather. One thread per query: perm indirection + 3 strided
// gathers, massively parallel (latency hidden by TLP). Removes the 2-round
// dependent gather from every knn wave's critical path.
// ---------------------------------------------------------------------------
__global__ __launch_bounds__(256) void gather_kernel(
    const float* __restrict__ p0, const float* __restrict__ p1,
    const float* __restrict__ wt, const int* __restrict__ perm,
    float4* __restrict__ newp, int N)
{
    const int q = blockIdx.x * 256 + threadIdx.x;
    const int b = q / N, n = q - b * N;
    const float wt0 = wt[b * 2];
    const int N0 = (int)(N * wt0);
    int j; const float* src;
    if (n < N0) { j = perm[(b * 2) * N + n];            src = p0; }
    else        { j = perm[(b * 2 + 1) * N + (n - N0)]; src = p1; }
    newp[q] = make_float4(src[(b * 3) * N + j], src[(b * 3 + 1) * N + j],
                          src[(b * 3 + 2) * N + j], 0.f);
}

// ---------------------------------------------------------------------------
// K1 helpers
// ---------------------------------------------------------------------------

// ballot-compact step: candidates with key<=T go to LDS slots (packed u64)
__device__ __forceinline__ void cpush(unsigned key, unsigned pos, unsigned Tu,
                                      bool valid, uint2* __restrict__ cc,
                                      int& cnt)
{
    const bool pred = valid && (key <= Tu);
    const unsigned long long bal = __ballot(pred);
    const unsigned below = __builtin_amdgcn_mbcnt_hi(
        (unsigned)(bal >> 32), __builtin_amdgcn_mbcnt_lo((unsigned)bal, 0u));
    const unsigned idx = (unsigned)cnt + below;
    if (pred && idx < 64u) cc[idx] = make_uint2(key, pos);
    cnt += (int)__popcll(bal);
}

// compaction scan over an arbitrary CSR range (expansion bins / remainders)
__device__ __forceinline__ void cscan(const float4* __restrict__ L,
                                      int bs, int be,
                                      float qx, float qy, float qz, float qq,
                                      unsigned Tu, uint2* __restrict__ cc,
                                      int& cnt, int lane)
{
    for (int p = bs; p < be; p += 64) {
        const int pos = p + lane;
        const float4 pc = L[min(pos, be - 1)];
        const float dt = fmaf(qz, pc.z, fmaf(qy, pc.y, qx * pc.x));
        const float d = fmaxf(fmaf(-2.f, dt, pc.w + qq), 0.f);
        cpush(__float_as_uint(d), (unsigned)pos, Tu, pos < be, cc, cnt);
    }
}

// dual-chain ballot-radix bisection: kk-th smallest key across 64 lanes.
// Exact order statistic (same value the bitonic T-sort produced).
__device__ __forceinline__ void bisect2(unsigned key0, unsigned key1,
                                        int kk0, int kk1,
                                        unsigned& t0, unsigned& t1)
{
    unsigned long long a0 = ~0ull, a1 = ~0ull;
    int n0 = kk0, n1 = kk1;
    unsigned p0 = 0, p1 = 0;
#pragma unroll
    for (int b = 30; b >= 0; --b) {               // bit31 (sign) always 0
        const unsigned long long bz0 = __ballot(!((key0 >> b) & 1u));
        const unsigned long long bz1 = __ballot(!((key1 >> b) & 1u));
        const unsigned long long zc0 = a0 & bz0, zc1 = a1 & bz1;
        const int c0 = __popcll(zc0), c1 = __popcll(zc1);
        const bool u0 = (c0 >= n0), u1 = (c1 >= n1);
        a0 = u0 ? zc0 : (a0 & ~bz0);
        a1 = u1 ? zc1 : (a1 & ~bz1);
        n0 = u0 ? n0 : n0 - c0;
        n1 = u1 ? n1 : n1 - c1;
        p0 |= u0 ? 0u : (1u << b);
        p1 |= u1 ? 0u : (1u << b);
    }
    t0 = p0; t1 = p1;
}

// tie resolution: alive = lanes with key==t*, kneed of them to take (smallest
// pos first). pos unique per lane -> pos-bisection is exact. Matches the
// verified pop-loop's (key,pos) selection order.
__device__ __forceinline__ unsigned long long tie_finish(
    unsigned long long alive, int kneed, unsigned tstar,
    unsigned key, unsigned pos)
{
    const unsigned long long less = __ballot(key < tstar);
    if (__popcll(alive) == kneed) return less | alive;   // common case
    unsigned long long a = alive; int n = kneed; unsigned pp = 0;
    for (int b = 11; b >= 0; --b) {                      // pos < 4096
        const unsigned long long bz = __ballot(!((pos >> b) & 1u));
        const unsigned long long zc = a & bz;
        const int c = __popcll(zc);
        const bool u = (c >= n);
        a = u ? zc : (a & ~bz);
        n = u ? n : n - c;
        pp |= u ? 0u : (1u << b);
    }
    return less | (alive & __ballot(pos <= pp));
}

// dual-chain exact top-kk selection masks among lane-held (key,pos)
__device__ __forceinline__ void sel2(unsigned key0, unsigned pos0,
                                     unsigned key1, unsigned pos1,
                                     int kk0, int kk1,
                                     unsigned long long& sel0,
                                     unsigned long long& sel1)
{
    unsigned long long a0 = ~0ull, a1 = ~0ull;
    int n0 = kk0, n1 = kk1;
    unsigned p0 = 0, p1 = 0;
#pragma unroll
    for (int b = 30; b >= 0; --b) {
        const unsigned long long bz0 = __ballot(!((key0 >> b) & 1u));
        const unsigned long long bz1 = __ballot(!((key1 >> b) & 1u));
        const unsigned long long zc0 = a0 & bz0, zc1 = a1 & bz1;
        const int c0 = __popcll(zc0), c1 = __popcll(zc1);
        const bool u0 = (c0 >= n0), u1 = (c1 >= n1);
        a0 = u0 ? zc0 : (a0 & ~bz0);
        a1 = u1 ? zc1 : (a1 & ~bz1);
        n0 = u0 ? n0 : n0 - c0;
        n1 = u1 ? n1 : n1 - c1;
        p0 |= u0 ? 0u : (1u << b);
        p1 |= u1 ? 0u : (1u << b);
    }
    sel0 = tie_finish(a0, n0, p0, key0, pos0);
    sel1 = tie_finish(a1, n1, p1, key1, pos1);
}

// ---- fallback path (cnt>64, astronomically rare): full-list queue scan ----
__device__ __forceinline__ void qpush(unsigned (&kh)[RQ], unsigned (&kl)[RQ],
                                      unsigned key, unsigned pos)
{
    bool cb[RQ];
#pragma unroll
    for (int s = 0; s < RQ; ++s) cb[s] = key < kh[s];
#pragma unroll
    for (int s = RQ - 1; s >= 1; --s) {
        kh[s] = cb[s - 1] ? kh[s - 1] : (cb[s] ? key : kh[s]);
        kl[s] = cb[s - 1] ? kl[s - 1] : (cb[s] ? pos : kl[s]);
    }
    kh[0] = cb[0] ? key : kh[0];
    kl[0] = cb[0] ? pos : kl[0];
}

__device__ __forceinline__ void pop_extract(
    unsigned (&kh)[RQ], unsigned (&kl)[RQ], int kk,
    const float4* __restrict__ L, int obase,
    float qx, float qy, float qz, float4* __restrict__ feat, int lane)
{
    unsigned mwin = 0;
    for (int rr = 0; rr < kk; ++rr) {
        unsigned gg = kh[0];
#pragma unroll
        for (int off = 32; off; off >>= 1) gg = min(gg, __shfl_xor(gg, off));
        const bool tied = (kh[0] == gg);
        unsigned mc;
        const unsigned long long bal = __ballot(tied);
        if (bal & (bal - 1)) {
            mc = tied ? kl[0] : 0xFFFFFFFFu;
#pragma unroll
            for (int off = 32; off; off >>= 1) mc = min(mc, __shfl_xor(mc, off));
        } else {
            mc = __shfl(kl[0], (int)__ffsll((long long)bal) - 1);
        }
        const bool w = tied && (kl[0] == mc);
        if (lane == rr) mwin = mc;
#pragma unroll
        for (int s = 0; s < RQ - 1; ++s) {
            kh[s] = w ? kh[s + 1] : kh[s];
            kl[s] = w ? kl[s + 1] : kl[s];
        }
        kh[RQ - 1] = w ? 0xFFFFFFFFu : kh[RQ - 1];
        kl[RQ - 1] = w ? 0xFFFFFFFFu : kl[RQ - 1];
    }
    if (lane < kk) {
        const float4 pc = L[mwin & 4095u];
        const float rx = pc.x - qx, ry = pc.y - qy, rz = pc.z - qz;
        feat[obase + lane] =
            make_float4(rx, ry, rz, sqrtf(fmaf(rx, rx, fmaf(ry, ry, rz * rz))));
    }
}

__device__ __forceinline__ void fallback_full(
    const float4* __restrict__ L, int Npts, int kk, int obase,
    float qx, float qy, float qz, float qq,
    float4* __restrict__ feat, int lane)
{
    unsigned kh[RQ], kl[RQ];
#pragma unroll
    for (int s = 0; s < RQ; ++s) { kh[s] = 0xFFFFFFFFu; kl[s] = 0xFFFFFFFFu; }
    for (int p = 0; p < Npts; p += 64) {
        const int pos = p + lane;
        const float4 pc = L[min(pos, Npts - 1)];
        const float dt = fmaf(qz, pc.z, fmaf(qy, pc.y, qx * pc.x));
        const float d = fmaxf(fmaf(-2.f, dt, pc.w + qq), 0.f);
        const unsigned key = (pos < Npts) ? __float_as_uint(d) : 0xFFFFFFFFu;
        qpush(kh, kl, key, (unsigned)pos);
    }
    pop_extract(kh, kl, kk, L, obase, qx, qy, qz, feat, lane);
}

// selected-lane feature write (order = rank in mask; downstream is
// permutation-invariant in k)
__device__ __forceinline__ void sel_write(
    unsigned long long sel, unsigned pos, const float4* __restrict__ L,
    int obase, float qx, float qy, float qz, float4* __restrict__ feat,
    int lane)
{
    if ((sel >> lane) & 1ull) {
        const int rank = __popcll(sel & ((1ull << lane) - 1ull));
        const float4 pc = L[pos & 4095u];
        const float rx = pc.x - qx, ry = pc.y - qy, rz = pc.z - qz;
        feat[obase + rank] =
            make_float4(rx, ry, rz, sqrtf(fmaf(rx, rx, fmaf(ry, ry, rz * rz))));
    }
}

// ---------------------------------------------------------------------------
// K1: exact kNN. One wave per query pair {(b,0,n),(b,1,n)} (kk0+kk1=32).
// Rank-space window (12 static chunks, keys in VGPRs) as in R4. This round:
// query gather hoisted to gather_kernel; T and the final top-kk selection via
// ballot-radix bisection (no shuffle networks); packed u64 LDS compaction.
// Selection set identical to the verified pop loop; cnt>64 -> exact fallback.
// ---------------------------------------------------------------------------
__global__ __launch_bounds__(256, 4) void knn_kernel(
    const float* __restrict__ wt,
    const float4* __restrict__ sp, const int* __restrict__ starts,
    float4* __restrict__ feat, const float4* __restrict__ newp, int N)
{
    __shared__ uint2 cc0s[256], cc1s[256];
    const int lane = threadIdx.x & 63;
    const int wv = threadIdx.x >> 6;
    const int gwave = (int)((blockIdx.x * 256 + threadIdx.x) >> 6); // pair id
    const int b = gwave / N;
    const int n = gwave - b * N;
    const int q = b * N + n;

    uint2* __restrict__ cc0 = cc0s + wv * 64;
    uint2* __restrict__ cc1 = cc1s + wv * 64;

    const float wt0 = __uint_as_float(__builtin_amdgcn_readfirstlane(
                          __float_as_uint(wt[b * 2])));
    const int k0 = (int)(32 * wt0);
    const int kk0 = k0, kk1 = 32 - k0;            // both in [8,24]

    const float4 qp = newp[q];                    // broadcast load
    const float qx = __uint_as_float(__builtin_amdgcn_readfirstlane(__float_as_uint(qp.x)));
    const float qy = __uint_as_float(__builtin_amdgcn_readfirstlane(__float_as_uint(qp.y)));
    const float qz = __uint_as_float(__builtin_amdgcn_readfirstlane(__float_as_uint(qp.z)));
    const float qq = qx * qx + qy * qy + qz * qz;

    const int bl0 = b * 2, bl1 = b * 2 + 1;
    const int stv0 = starts[bl0 * 65 + lane];     // lane j holds starts[j]
    const int stv1 = starts[bl1 * 65 + lane];

    // query bin via one ballot over the constant boundary table
    const float bv = (lane < 63) ? ZB[lane] : 3.0e38f;
    const int qbin = __popcll(__ballot(qz >= bv));    // 0..63

    const float4* L0 = sp + (size_t)bl0 * 4096;
    const float4* L1 = sp + (size_t)bl1 * 4096;

    // rank windows centered on the query bin's rank midpoint
    const int st0 = __shfl(stv0, qbin);
    const int en0 = (qbin >= 63) ? N : __shfl(stv0, qbin + 1);
    const int st1 = __shfl(stv1, qbin);
    const int en1 = (qbin >= 63) ? N : __shfl(stv1, qbin + 1);
    int s0 = ((st0 + en0) >> 1) - WRANKS / 2;
    s0 = s0 < 0 ? 0 : (s0 > N - WRANKS ? N - WRANKS : s0);
    int s1 = ((st1 + en1) >> 1) - WRANKS / 2;
    s1 = s1 < 0 ? 0 : (s1 > N - WRANKS ? N - WRANKS : s1);
    const int e0 = s0 + WRANKS, e1 = s1 + WRANKS;

    // ---- pass A: 12 static chunks per list, keys kept in VGPRs ----
    const float4* Lb0 = L0 + s0 + lane;
    const float4* Lb1 = L1 + s1 + lane;
    unsigned k0v[WCH], k1v[WCH];
    unsigned mn0 = 0xFFFFFFFFu, mn1 = 0xFFFFFFFFu;
    {
        float4 A0[3], A1[3], B0[3], B1[3];
#pragma unroll
        for (int c = 0; c < 3; ++c) { A0[c] = Lb0[c << 6]; A1[c] = Lb1[c << 6]; }
#pragma unroll
        for (int g = 0; g < 4; ++g) {
            if (g < 3) {
#pragma unroll
                for (int c = 0; c < 3; ++c) {
                    B0[c] = Lb0[(g * 3 + 3 + c) << 6];
                    B1[c] = Lb1[(g * 3 + 3 + c) << 6];
                }
            }
#pragma unroll
            for (int c = 0; c < 3; ++c) {
                const int ch = g * 3 + c;
                {
                    const float dt = fmaf(qz, A0[c].z, fmaf(qy, A0[c].y, qx * A0[c].x));
                    k0v[ch] = __float_as_uint(fmaxf(fmaf(-2.f, dt, A0[c].w + qq), 0.f));
                    mn0 = min(mn0, k0v[ch]);
                }
                {
                    const float dt = fmaf(qz, A1[c].z, fmaf(qy, A1[c].y, qx * A1[c].x));
                    k1v[ch] = __float_as_uint(fmaxf(fmaf(-2.f, dt, A1[c].w + qq), 0.f));
                    mn1 = min(mn1, k1v[ch]);
                }
            }
            if (g < 3) {
#pragma unroll
                for (int c = 0; c < 3; ++c) { A0[c] = B0[c]; A1[c] = B1[c]; }
            }
        }
    }

    // ---- T = m_(kk): dual ballot-radix bisection of the 64 lane-mins ----
    unsigned Tu0, Tu1;
    bisect2(mn0, mn1, kk0, kk1, Tu0, Tu1);
    const float T0f = __uint_as_float(Tu0);
    const float T1f = __uint_as_float(Tu1);

    // ---- compaction from registers (no reload / recompute) ----
    int cnt0 = 0, cnt1 = 0;
#pragma unroll
    for (int ch = 0; ch < WCH; ++ch) {
        cpush(k0v[ch], (unsigned)(s0 + (ch << 6) + lane), Tu0, true, cc0, cnt0);
        cpush(k1v[ch], (unsigned)(s1 + (ch << 6) + lane), Tu1, true, cc1, cnt1);
    }

    // ---- outside the window: partial-bin remainders + bin-edge expansion ----
    {
        // list 0
        const int binL = __popcll(__ballot(stv0 <= s0)) - 1;    // bin of rank s0
        if (s0 > 0) {
            const int bs = __shfl(stv0, binL);
            if (bs < s0) cscan(L0, bs, s0, qx, qy, qz, qq, Tu0, cc0, cnt0, lane);
            for (int jb = binL - 1; jb >= 0; --jb) {
                const float dz = qz - ZB[jb];
                if (dz * dz * 0.99999f > T0f) break;
                const int bs2 = __shfl(stv0, jb);
                const int be2 = __shfl(stv0, jb + 1);
                cscan(L0, bs2, be2, qx, qy, qz, qq, Tu0, cc0, cnt0, lane);
            }
        }
        if (e0 < N) {
            const int binR = __popcll(__ballot(stv0 <= e0)) - 1; // bin of rank e0
            const int re = (binR >= 63) ? N : __shfl(stv0, binR + 1);
            if (e0 < re) cscan(L0, e0, re, qx, qy, qz, qq, Tu0, cc0, cnt0, lane);
            for (int jb = binR + 1; jb <= 63; ++jb) {
                const float dz = ZB[jb - 1] - qz;
                if (dz * dz * 0.99999f > T0f) break;
                const int bs2 = __shfl(stv0, jb);
                const int be2 = (jb >= 63) ? N : __shfl(stv0, jb + 1);
                cscan(L0, bs2, be2, qx, qy, qz, qq, Tu0, cc0, cnt0, lane);
            }
        }
        // list 1
        const int binL1 = __popcll(__ballot(stv1 <= s1)) - 1;
        if (s1 > 0) {
            const int bs = __shfl(stv1, binL1);
            if (bs < s1) cscan(L1, bs, s1, qx, qy, qz, qq, Tu1, cc1, cnt1, lane);
            for (int jb = binL1 - 1; jb >= 0; --jb) {
                const float dz = qz - ZB[jb];
                if (dz * dz * 0.99999f > T1f) break;
                const int bs2 = __shfl(stv1, jb);
                const int be2 = __shfl(stv1, jb + 1);
                cscan(L1, bs2, be2, qx, qy, qz, qq, Tu1, cc1, cnt1, lane);
            }
        }
        if (e1 < N) {
            const int binR1 = __popcll(__ballot(stv1 <= e1)) - 1;
            const int re = (binR1 >= 63) ? N : __shfl(stv1, binR1 + 1);
            if (e1 < re) cscan(L1, e1, re, qx, qy, qz, qq, Tu1, cc1, cnt1, lane);
            for (int jb = binR1 + 1; jb <= 63; ++jb) {
                const float dz = ZB[jb - 1] - qz;
                if (dz * dz * 0.99999f > T1f) break;
                const int bs2 = __shfl(stv1, jb);
                const int be2 = (jb >= 63) ? N : __shfl(stv1, jb + 1);
                cscan(L1, bs2, be2, qx, qy, qz, qq, Tu1, cc1, cnt1, lane);
            }
        }
    }

    // ---- finalize: dual bisection top-kk selection, per-lane writes ----
    const int ob0 = (q << 5), ob1 = (q << 5) + k0;
    if ((cnt0 <= 64) && (cnt1 <= 64)) {
        const uint2 v0 = cc0[lane];
        const uint2 v1 = cc1[lane];
        const unsigned ky0 = (lane < cnt0) ? v0.x : 0xFFFFFFFFu;
        const unsigned ps0 = (lane < cnt0) ? v0.y : 0xFFFFFFFFu;
        const unsigned ky1 = (lane < cnt1) ? v1.x : 0xFFFFFFFFu;
        const unsigned ps1 = (lane < cnt1) ? v1.y : 0xFFFFFFFFu;
        unsigned long long sel0, sel1;
        sel2(ky0, ps0, ky1, ps1, kk0, kk1, sel0, sel1);
        sel_write(sel0, ps0, L0, ob0, qx, qy, qz, feat, lane);
        sel_write(sel1, ps1, L1, ob1, qx, qy, qz, feat, lane);
    } else {                                      // rare: exact fallback
        if (cnt0 <= 64) {
            const uint2 v0 = cc0[lane];
            const unsigned ky = (lane < cnt0) ? v0.x : 0xFFFFFFFFu;
            const unsigned ps = (lane < cnt0) ? v0.y : 0xFFFFFFFFu;
            unsigned long long sa, sb;
            sel2(ky, ps, ky, ps, kk0, kk0, sa, sb);
            sel_write(sa, ps, L0, ob0, qx, qy, qz, feat, lane);
        } else {
            fallback_full(L0, N, kk0, ob0, qx, qy, qz, qq, feat, lane);
        }
        if (cnt1 <= 64) {
            const uint2 v1 = cc1[lane];
            const unsigned ky = (lane < cnt1) ? v1.x : 0xFFFFFFFFu;
            const unsigned ps = (lane < cnt1) ? v1.y : 0xFFFFFFFFu;
            unsigned long long sa, sb;
            sel2(ky, ps, ky, ps, kk1, kk1, sa, sb);
            sel_write(sa, ps, L1, ob1, qx, qy, qz, feat, lane);
        } else {
            fallback_full(L1, N, kk1, ob1, qx, qy, qz, qq, feat, lane);
        }
    }
}

// ---------------------------------------------------------------------------
// K2: per-sample feature moments (S=sum f [4], M=sum f f^T [10]).
// ---------------------------------------------------------------------------
__global__ __launch_bounds__(256) void moment_stats_kernel(
    const float4* __restrict__ feat, float* __restrict__ stats1, int N)
{
    const int t = threadIdx.x, lane = t & 63;
    const int bpb = 64;
    const int b = blockIdx.x / bpb;
    const int ppb = (N * 32) / bpb;
    const size_t base = (size_t)b * N * 32 + (size_t)(blockIdx.x % bpb) * ppb;
    float a[14];
#pragma unroll
    for (int i = 0; i < 14; ++i) a[i] = 0.f;
    for (int i = t; i < ppb; i += 256) {
        const float4 f = feat[base + i];
        a[0] += f.x; a[1] += f.y; a[2] += f.z; a[3] += f.w;
        a[4] = fmaf(f.x, f.x, a[4]);  a[5] = fmaf(f.x, f.y, a[5]);
        a[6] = fmaf(f.x, f.z, a[6]);  a[7] = fmaf(f.x, f.w, a[7]);
        a[8] = fmaf(f.y, f.y, a[8]);  a[9] = fmaf(f.y, f.z, a[9]);
        a[10] = fmaf(f.y, f.w, a[10]); a[11] = fmaf(f.z, f.z, a[11]);
        a[12] = fmaf(f.z, f.w, a[12]); a[13] = fmaf(f.w, f.w, a[13]);
    }
#pragma unroll
    for (int i = 0; i < 14; ++i) {
        float x = a[i];
#pragma unroll
        for (int o = 32; o; o >>= 1) x += __shfl_down(x, o);
        a[i] = x;
    }
    __shared__ float sm[14];
    if (t < 14) sm[t] = 0.f;
    __syncthreads();
    if (lane == 0) {
#pragma unroll
        for (int i = 0; i < 14; ++i) atomicAdd(&sm[i], a[i]);
    }
    __syncthreads();
    if (t < 14) atomicAdd(&stats1[b * 14 + t], sm[t]);
}

// ---------------------------------------------------------------------------
// K3/K4: conv1+gn1+relu -> bf16 h in LDS -> conv2 via MFMA 16x16x32
// ---------------------------------------------------------------------------
template <int MODE>
__global__ __launch_bounds__(256) void conv2_pass_kernel(
    const float4* __restrict__ feat,
    const float* __restrict__ w1, const float* __restrict__ b1,
    const float* __restrict__ gn1w, const float* __restrict__ gn1b,
    const float* __restrict__ stats1,
    const float* __restrict__ w2, const float* __restrict__ b2,
    const float* __restrict__ gn2w, const float* __restrict__ gn2b,
    float* __restrict__ stats2,
    const float4* __restrict__ newp, float* __restrict__ out,
    int N, float inv_cnt)
{
    const int t = threadIdx.x, lane = t & 63, wv = t >> 6;
    const int quad = lane >> 4, col = lane & 15;
    const int bpb = (N * 32) / 512;
    const int b = blockIdx.x / bpb;
    const int pblock = (blockIdx.x - b * bpb) * 512;
    const size_t pbase = (size_t)b * N * 32 + pblock + wv * 128;

    __shared__ float sfin[24];
    __shared__ float sacc[16];
    __shared__ unsigned short h_lds[512 * 40];
    __shared__ float ssc[512];

    if (t < 16) sacc[t] = 0.f;
    if (t < 4) {
        const float cnt = (float)(N * 32);
        const float* mm = stats1 + b * 14;
        const float S0 = mm[0], S1 = mm[1], S2 = mm[2], S3 = mm[3];
        float sum = 0.f, sq = 0.f;
        for (int cch = 0; cch < 8; ++cch) {
            const int cid = t * 8 + cch;
            const float4 w = ((const float4*)w1)[cid];
            const float bb = b1[cid];
            const float ws = w.x * S0 + w.y * S1 + w.z * S2 + w.w * S3;
            const float wMw =
                w.x * w.x * mm[4] + w.y * w.y * mm[8] + w.z * w.z * mm[11] +
                w.w * w.w * mm[13] +
                2.f * (w.x * w.y * mm[5] + w.x * w.z * mm[6] + w.x * w.w * mm[7] +
                       w.y * w.z * mm[9] + w.y * w.w * mm[10] + w.z * w.w * mm[12]);
            sum += cnt * bb + ws;
            sq += cnt * bb * bb + 2.f * bb * ws + wMw;
        }
        const float mu = sum * inv_cnt, var = sq * inv_cnt - mu * mu;
        sfin[2 * t] = mu; sfin[2 * t + 1] = rsqrtf(var + 1e-5f);
    }
    if (MODE == 1 && t >= 4 && t < 12) {
        const int g = t - 4;
        const float S = stats2[b * 16 + g], Q = stats2[b * 16 + 8 + g];
        const float mu = S * inv_cnt, var = Q * inv_cnt - mu * mu;
        sfin[8 + 2 * g] = mu; sfin[8 + 2 * g + 1] = rsqrtf(var + 1e-5f);
    }
    __syncthreads();

    const int c1 = lane & 31, pt = lane >> 5;
    const float4 w1r = ((const float4*)w1)[c1];
    const float b1c = b1[c1];
    const int g1 = c1 >> 3;
    const float sc1 = sfin[2 * g1 + 1] * gn1w[c1];
    const float sh1 = gn1b[c1] - sfin[2 * g1] * sc1;

    for (int it = 0; it < 64; ++it) {
        const size_t p = pbase + it * 2;
        const float4 f = feat[p + pt];
        const float y = b1c + w1r.x * f.x + w1r.y * f.y + w1r.z * f.z + w1r.w * f.w;
        const float h = fmaxf(0.f, fmaf(y, sc1, sh1));
        h_lds[(wv * 128 + it * 2 + pt) * 40 + c1] = f2bf(h);
    }

    s8v afr[4];
#pragma unroll
    for (int T = 0; T < 4; ++T) {
        const int row = T * 16 + col;
#pragma unroll
        for (int j2 = 0; j2 < 8; ++j2)
            afr[T][j2] = (short)f2bf(w2[row * 32 + quad * 8 + j2]);
    }

    float b2v[4][4], sc2v[4][4], sh2v[4][4];
#pragma unroll
    for (int T = 0; T < 4; ++T)
#pragma unroll
        for (int r4 = 0; r4 < 4; ++r4) {
            const int cch = T * 16 + quad * 4 + r4;
            b2v[T][r4] = b2[cch];
            if (MODE == 1) {
                const int g2 = cch >> 3;
                const float sc = sfin[8 + 2 * g2 + 1] * gn2w[cch];
                sc2v[T][r4] = sc;
                sh2v[T][r4] = gn2b[cch] - sfin[8 + 2 * g2] * sc + b2[cch] * sc;
            }
        }

    float gsum[4] = {0, 0, 0, 0}, gsq[4] = {0, 0, 0, 0};

    for (int pt16 = 0; pt16 < 8; ++pt16) {
        const int row = wv * 128 + pt16 * 16 + col;
        const s8v bfr = *(const s8v*)&h_lds[row * 40 + quad * 8];
        f32x4 acc[4];
#pragma unroll
        for (int T = 0; T < 4; ++T) {
            acc[T] = (f32x4){0.f, 0.f, 0.f, 0.f};
            acc[T] = __builtin_amdgcn_mfma_f32_16x16x32_bf16(afr[T], bfr, acc[T], 0, 0, 0);
        }
        if (MODE == 0) {
#pragma unroll
            for (int T = 0; T < 4; ++T)
#pragma unroll
                for (int r4 = 0; r4 < 4; ++r4) {
                    const float v = acc[T][r4] + b2v[T][r4];
                    gsum[T] += v;
                    gsq[T] = fmaf(v, v, gsq[T]);
                }
        } else {
            float s = -3.0e38f;
#pragma unroll
            for (int T = 0; T < 4; ++T)
#pragma unroll
                for (int r4 = 0; r4 < 4; ++r4)
                    s = fmaxf(s, fmaxf(0.f, fmaf(acc[T][r4], sc2v[T][r4], sh2v[T][r4])));
            s = fmaxf(s, __shfl_xor(s, 16));
            s = fmaxf(s, __shfl_xor(s, 32));
            if (quad == 0) ssc[wv * 128 + pt16 * 16 + col] = s;
        }
    }

    if (MODE == 0) {
#pragma unroll
        for (int T = 0; T < 4; ++T) {
#pragma unroll
            for (int o = 1; o < 16; o <<= 1) {
                gsum[T] += __shfl_xor(gsum[T], o);
                gsq[T] += __shfl_xor(gsq[T], o);
            }
            gsum[T] += __shfl_xor(gsum[T], 16);
            gsq[T] += __shfl_xor(gsq[T], 16);
        }
        if (lane == 0) {
#pragma unroll
            for (int T = 0; T < 4; ++T) {
                atomicAdd(&sacc[2 * T], gsum[T]);
                atomicAdd(&sacc[8 + 2 * T], gsq[T]);
            }
        }
        if (lane == 32) {
#pragma unroll
            for (int T = 0; T < 4; ++T) {
                atomicAdd(&sacc[2 * T + 1], gsum[T]);
                atomicAdd(&sacc[8 + 2 * T + 1], gsq[T]);
            }
        }
        __syncthreads();
        if (t < 16) atomicAdd(&stats2[b * 16 + t], sacc[t]);
    } else {
        __syncthreads();
        const int qi = t >> 4, sub = t & 15;
        const int qg = (b * N * 32 + pblock) / 32 + qi;
        const int n = qg - b * N;
        const float s0 = ssc[qi * 32 + sub], s1 = ssc[qi * 32 + 16 + sub];
        float mx = fmaxf(s0, s1);
#pragma unroll
        for (int o = 8; o; o >>= 1) mx = fmaxf(mx, __shfl_xor(mx, o));
        const float e0 = __expf(s0 - mx), e1 = __expf(s1 - mx);
        float ssum = e0 + e1;
#pragma unroll
        for (int o = 8; o; o >>= 1) ssum += __shfl_xor(ssum, o);
        const float4 qc = newp[qg];
        const float4 f0 = feat[(size_t)qg * 32 + sub];
        const float4 f1 = feat[(size_t)qg * 32 + 16 + sub];
        float ax = e0 * (qc.x + f0.x) + e1 * (qc.x + f1.x);
        float ay = e0 * (qc.y + f0.y) + e1 * (qc.y + f1.y);
        float az = e0 * (qc.z + f0.z) + e1 * (qc.z + f1.z);
#pragma unroll
        for (int o = 8; o; o >>= 1) {
            ax += __shfl_xor(ax, o);
            ay += __shfl_xor(ay, o);
            az += __shfl_xor(az, o);
        }
        if (sub == 0) {
            const float inv = 1.f / ssum;
            out[(b * 3 + 0) * N + n] = ax * inv;
            out[(b * 3 + 1) * N + n] = ay * inv;
            out[(b * 3 + 2) * N + n] = az * inv;
        }
    }
}

// ---------------------------------------------------------------------------
extern "C" void kernel_launch(void* const* d_in, const int* in_sizes, int n_in,
                              void* d_out, int out_size, void* d_ws, size_t ws_size,
                              hipStream_t stream)
{
    const float* p0   = (const float*)d_in[0];
    const float* p1   = (const float*)d_in[1];
    const float* wt   = (const float*)d_in[3];
    const int*   perm = (const int*)d_in[4];
    const float* w1   = (const float*)d_in[5];
    const float* b1   = (const float*)d_in[6];
    const float* gn1w = (const float*)d_in[7];
    const float* gn1b = (const float*)d_in[8];
    const float* w2   = (const float*)d_in[9];
    const float* b2   = (const float*)d_in[10];
    const float* gn2w = (const float*)d_in[11];
    const float* gn2b = (const float*)d_in[12];
    float* out = (float*)d_out;

    const int B = in_sizes[3] / 2;
    const int N = in_sizes[0] / (3 * B);

    // workspace layout
    char* ws = (char*)d_ws;
    float4* spts = (float4*)ws;               // B*2*4096 float4 (z-binned CSR)
    size_t off = (size_t)B * 2 * 4096 * sizeof(float4);
    float4* feat = (float4*)(ws + off);       off += (size_t)B * N * 32 * sizeof(float4);
    float4* newp = (float4*)(ws + off);       off += (size_t)B * N * sizeof(float4);
    float* stats1 = (float*)(ws + off);       off += (size_t)B * 14 * sizeof(float);
    float* stats2 = (float*)(ws + off);       off += (size_t)B * 16 * sizeof(float);
    int* starts = (int*)(ws + off);           // B*2*65 CSR offsets

    hipMemsetAsync(stats1, 0, (size_t)B * 30 * sizeof(float), stream);

    const float inv_cnt = 1.f / (8.f * (float)N * 32.f);

    gather_kernel<<<(B * N) / 256, 256, 0, stream>>>(p0, p1, wt, perm, newp, N);

    zbin_kernel<<<B * 2, 1024, 0, stream>>>(p0, p1, spts, starts, N);

    // one wave per query pair -> B*N waves -> B*N/4 blocks of 256 threads
    knn_kernel<<<(B * N) / 4, 256, 0, stream>>>(
        wt, spts, starts, feat, newp, N);

    moment_stats_kernel<<<B * 64, 256, 0, stream>>>(feat, stats1, N);

    conv2_pass_kernel<0><<<(B * N * 32) / 512, 256, 0, stream>>>(
        feat, w1, b1, gn1w, gn1b, stats1, w2, b2, gn2w, gn2b, stats2,
        newp, out, N, inv_cnt);

    conv2_pass_kernel<1><<<(B * N * 32) / 512, 256, 0, stream>>>(
        feat, w1, b1, gn1w, gn1b, stats1, w2, b2, gn2w, gn2b, stats2,
        newp, out, N, inv_cnt);
}